// Round 20
// baseline (161.925 us; speedup 1.0000x reference)
//
#include <hip/hip_runtime.h>
#include <hip/hip_bf16.h>

#define B_ 16
#define S_ 4096
#define C_ 320
#define KK_ 77
#define D_ 768
#define H_ 8
#define DH_ 40
#define KP_ 80           // padded keys per head
#define NP_ (H_ * KP_)   // 640
#define TAU_ 0.1f
#define GAMMA_ 1.0f
#define EPS_ 1e-12f

typedef __bf16 bf16x8 __attribute__((ext_vector_type(8)));
typedef float f32x4 __attribute__((ext_vector_type(4)));
typedef unsigned short ushort8v __attribute__((ext_vector_type(8)));
typedef unsigned int u32;

#define WAITV(N)  asm volatile("s_waitcnt vmcnt(" #N ")" ::: "memory")
#define WAITVL(N) asm volatile("s_waitcnt vmcnt(" #N ") lgkmcnt(0)" ::: "memory")
#define WAITLG()  asm volatile("s_waitcnt lgkmcnt(0)" ::: "memory")
#define BAR()     __builtin_amdgcn_s_barrier()

__device__ __forceinline__ unsigned short f2bf(float f) {
    union { float f; unsigned u; } v; v.f = f;
    unsigned r = v.u + 0x7fffu + ((v.u >> 16) & 1u);
    return (unsigned short)(r >> 16);
}

// async 16B-per-lane global->LDS DMA (lds dest = wave-uniform base + lane*16)
__device__ __forceinline__ void gld16(const void* g, char* l) {
    __builtin_amdgcn_global_load_lds(
        (const __attribute__((address_space(1))) u32*)g,
        (__attribute__((address_space(3))) u32*)l, 16, 0, 0);
}

// ---------------------------------------------------------------- build_M
// 40-col windows: grid (3, 8, 16)
__global__ __launch_bounds__(256) void build_M(const float* __restrict__ Wq,
        const float* __restrict__ Wk, const float* __restrict__ Wv,
        const float* __restrict__ Wo, unsigned short* __restrict__ Bmat) {
    const int Dk = blockIdx.x * 256 + threadIdx.x;     // 0..767
    const int h = blockIdx.y;
    const int which = blockIdx.z >> 3;
    const int c0 = (blockIdx.z & 7) * 40;
    __shared__ float wlds[40 * 44];
    for (int i = threadIdx.x; i < 40 * DH_; i += 256) {
        int c = i / DH_, d = i % DH_;
        wlds[c * 44 + d] = which
            ? Wo[(size_t)(h * DH_ + d) * C_ + (c0 + c)]
            : Wq[(size_t)(c0 + c) * C_ + h * DH_ + d];
    }
    float a[DH_];
    const float* Arow = (which ? Wv : Wk) + (size_t)Dk * C_ + h * DH_;
    #pragma unroll
    for (int d = 0; d < DH_; ++d) a[d] = Arow[d];
    __syncthreads();
    const float scale = 0.15811388300841898f;          // 1/sqrt(40)
    for (int c = 0; c < 40; ++c) {
        float s = 0.f;
        #pragma unroll
        for (int q = 0; q < 10; ++q) {
            float4 wv4 = *(const float4*)&wlds[c * 44 + q * 4];
            s += a[q * 4 + 0] * wv4.x + a[q * 4 + 1] * wv4.y
               + a[q * 4 + 2] * wv4.z + a[q * 4 + 3] * wv4.w;
        }
        if (!which) s *= scale;
        int n = which * 2560 + h * C_ + c0 + c;
        Bmat[(size_t)n * D_ + Dk] = f2bf(s);
    }
}

// ---------------------------------------------------------------- gemm_WpU
// 320 blocks x 512 threads (16b x 20nt). A staged directly from ehs f32
// (inline f32->bf16 convert, kk>=77 zeroed). nt==0 blocks compute penalty.
__global__ __launch_bounds__(512) void gemm_WpU(
        const float* __restrict__ ehs, const float* __restrict__ harm,
        const unsigned short* __restrict__ Bmat,
        unsigned short* __restrict__ Wp, unsigned short* __restrict__ U,
        float* __restrict__ pen) {
    const int id = blockIdx.x;               // 320 = 16 b * 20 nt
    const int b = id & 15, nt = id >> 4;
    const int tid = threadIdx.x, w = tid >> 6, l = tid & 63;
    const int lrow = l & 15, lgrp = l >> 4, lk = lgrp * 8;
    __shared__ unsigned short Al[80 * 768];  // 122880 B, swizzled
    char* lds = (char*)Al;

    const float* Eb = ehs + (size_t)b * KK_ * D_;
    #pragma unroll
    for (int it = 0; it < 15; ++it) {
        int ch = tid + it * 512;             // 0..7679
        int kk = ch / 96, c8 = ch % 96;
        ushort8v v8 = (ushort8v)(unsigned short)0;
        if (kk < KK_) {
            const float4* src = (const float4*)(Eb + (size_t)kk * D_ + c8 * 8);
            float4 a0 = src[0], a1 = src[1];
            v8[0] = f2bf(a0.x); v8[1] = f2bf(a0.y);
            v8[2] = f2bf(a0.z); v8[3] = f2bf(a0.w);
            v8[4] = f2bf(a1.x); v8[5] = f2bf(a1.y);
            v8[6] = f2bf(a1.z); v8[7] = f2bf(a1.w);
        }
        int a = (ch * 16) ^ ((kk & 7) << 4);
        *(ushort8v*)(lds + a) = v8;
    }

    if (nt == 0) {
        for (int kk = w; kk < KP_; kk += 8) {
            if (kk < KK_) {
                const float* er = Eb + (size_t)kk * D_;
                float ss = 0.f, dd = 0.f, hh = 0.f;
                #pragma unroll
                for (int j = 0; j < 12; ++j) {
                    float e = er[l + j * 64], hv = harm[l + j * 64];
                    ss += e * e; dd += e * hv; hh += hv * hv;
                }
                #pragma unroll
                for (int off = 32; off; off >>= 1) {
                    ss += __shfl_xor(ss, off);
                    dd += __shfl_xor(dd, off);
                    hh += __shfl_xor(hh, off);
                }
                if (l == 0) {
                    float cs = dd / (fmaxf(sqrtf(ss), EPS_) * fmaxf(sqrtf(hh), EPS_));
                    pen[b * KP_ + kk] = GAMMA_ * fmaxf(cs - TAU_, 0.f);
                }
            } else if (l == 0) {
                pen[b * KP_ + kk] = 0.f;
            }
        }
    }

    const int n0 = nt * 256 + w * 32;
    const unsigned short* Br = Bmat + (size_t)(n0 + lrow) * D_ + lk;
    bf16x8 bC[2], bN[2];
    #pragma unroll
    for (int nf = 0; nf < 2; ++nf)
        bC[nf] = *(const bf16x8*)(Br + (size_t)nf * 16 * D_);
    __syncthreads();

    f32x4 acc[5][2];
    #pragma unroll
    for (int mf = 0; mf < 5; ++mf)
        #pragma unroll
        for (int nf = 0; nf < 2; ++nf) acc[mf][nf] = (f32x4){0.f, 0.f, 0.f, 0.f};
    #pragma unroll
    for (int ks = 0; ks < D_ / 32; ++ks) {
        if (ks < D_ / 32 - 1) {
            #pragma unroll
            for (int nf = 0; nf < 2; ++nf)
                bN[nf] = *(const bf16x8*)(Br + (size_t)nf * 16 * D_ + (ks + 1) * 32);
        }
        bf16x8 af[5];
        #pragma unroll
        for (int mf = 0; mf < 5; ++mf) {
            int row = mf * 16 + lrow;
            int a = (row * 1536 + (ks * 32 + lk) * 2) ^ ((row & 7) << 4);
            af[mf] = *(const bf16x8*)(lds + a);
        }
        __builtin_amdgcn_s_setprio(1);
        #pragma unroll
        for (int mf = 0; mf < 5; ++mf)
            #pragma unroll
            for (int nf = 0; nf < 2; ++nf)
                acc[mf][nf] = __builtin_amdgcn_mfma_f32_16x16x32_bf16(
                    af[mf], bC[nf], acc[mf][nf], 0, 0, 0);
        __builtin_amdgcn_s_setprio(0);
        #pragma unroll
        for (int nf = 0; nf < 2; ++nf) bC[nf] = bN[nf];
    }
    #pragma unroll
    for (int nf = 0; nf < 2; ++nf) {
        const int col = n0 + nf * 16 + lrow;
        if (col < 2560) {
            const int h = col / C_, c = col % C_;
            #pragma unroll
            for (int mf = 0; mf < 5; ++mf)
                #pragma unroll
                for (int r = 0; r < 4; ++r) {
                    int kk = mf * 16 + lgrp * 4 + r;
                    Wp[((size_t)b * NP_ + h * KP_ + kk) * C_ + c] = f2bf(acc[mf][nf][r]);
                }
        } else {
            const int n2 = col - 2560;
            const int h = n2 / C_, c = n2 % C_;
            #pragma unroll
            for (int mf = 0; mf < 5; ++mf)
                #pragma unroll
                for (int r = 0; r < 4; ++r) {
                    int kk = mf * 16 + lgrp * 4 + r;
                    U[((size_t)b * C_ + c) * NP_ + h * KP_ + kk] = f2bf(acc[mf][nf][r]);
                }
        }
    }
}

// ---------------------------------------------------------------- fused attn
// R19: R12 structure with hs staged AS F32 via global_load_lds (async, no reg
// round-trip), overlapped with Wp slice-0 DMA; fragments converted f32->bf16
// in the K-loop. HS-f32 [64][1280B] 80KB (swizzle ^((r&7)<<4), inverse on DMA
// source) + WB 80KB. Phase 2 byte-identical (PB over HS, U bufs over WB).
__global__ __launch_bounds__(512, 2) void fused_attn(
        const float* __restrict__ hs, const unsigned short* __restrict__ Wp,
        const unsigned short* __restrict__ U, const float* __restrict__ pen,
        const float* __restrict__ bo, float* __restrict__ out) {
    const int id = blockIdx.x;                  // 1024 = 8 xcd * 128
    const int xcd = id & 7, rest = id >> 3;
    const int b = xcd * 2 + (rest >> 6);        // 2 batches per XCD
    const int s0 = (rest & 63) * 64;
    __shared__ __align__(16) char smem[163840];
    char* HS = smem;                            // [0,81920)   hs f32 tile (ph1)
    char* WB = smem + 81920;                    // [81920,163840) Wp K=64 slice
    char* PB = smem;                            // [0,81920)   P (phase 2)
    char* U0 = smem + 81920;                    // [81920,122880)  U slice buf
    char* U1 = smem + 122880;                   // [122880,163840) U slice buf
    const int tid = threadIdx.x, w = tid >> 6, l = tid & 63;
    const int lrow = l & 15, lgrp = l >> 4, lk = lgrp * 8;
    const int h = w;                            // phase-1: wave = head
    const int mgrp = w & 1, ngrp = w >> 1;      // phase-2: 2m x 4n

    const unsigned short* Wpb = Wp + ((size_t)b * NP_) * C_;
    const unsigned short* Ub  = U  + ((size_t)b * C_) * NP_;
    const char* Hb = (const char*)(hs + ((size_t)b * S_ + s0) * C_);

    // hs f32 tile -> HS [64 r][1280B]; 16B chunk i of row r stored at
    // (r*1280 + i*16) with SOURCE offset (i*16)^((r&7)<<4). 10 instr/wave.
    auto stage_hs = [&]() {
        #pragma unroll
        for (int j = 0; j < 10; ++j) {
            int ch = w * 640 + j * 64 + l;      // 0..5119
            int r = ch / 80, i = ch % 80;
            int x = (i * 16) ^ ((r & 7) << 4);
            gld16(Hb + (size_t)r * 1280 + x, HS + ch * 16);
        }
    };
    // Wp K=64 slice s -> WB [n 640][128B]; src chunk (q^(n&7)). 10 instr/wave.
    auto stage_wp = [&](int s) {
        #pragma unroll
        for (int j = 0; j < 10; ++j) {
            int ch = w * 640 + j * 64 + l;      // 0..5119
            int n = ch >> 3, q = ch & 7;
            gld16(Wpb + (size_t)n * C_ + s * 64 + ((q ^ (n & 7)) << 3),
                  WB + ch * 16);
        }
    };
    // U K=64 slice t -> [c 320][128B]; src chunk (q^(c&7)). 5 instr/wave.
    auto stage_u = [&](int t, char* buf) {
        #pragma unroll
        for (int j = 0; j < 5; ++j) {
            int ch = w * 320 + j * 64 + l;      // 0..2559
            int c = ch >> 3, q = ch & 7;
            gld16(Ub + (size_t)c * NP_ + t * 64 + ((q ^ (c & 7)) << 3),
                  buf + ch * 16);
        }
    };

    // ---- prologue: pen loads + hs DMA + Wp slice-0 DMA, all concurrent
    float4 pv4[5];
    #pragma unroll
    for (int nf = 0; nf < 5; ++nf)
        pv4[nf] = *(const float4*)(pen + b * KP_ + nf * 16 + lgrp * 4);
    stage_hs();
    stage_wp(0);

    // ---- phase 1: D[kk][m], 5 K=64 slices, single buf; DMA(s+1) || MFMA(s)
    f32x4 acc[5][4];
    #pragma unroll
    for (int nf = 0; nf < 5; ++nf)
        #pragma unroll
        for (int mf = 0; mf < 4; ++mf) acc[nf][mf] = (f32x4){0.f, 0.f, 0.f, 0.f};
    #pragma unroll
    for (int s = 0; s < 5; ++s) {
        WAITV(0);                               // own DMA (incl. hs at s=0) done
        BAR();                                  // slice s (+hs) fully landed
        bf16x8 bC[5][2];
        f32x4 hraw[4][2][2];
        #pragma unroll
        for (int nf = 0; nf < 5; ++nf) {
            int n = h * KP_ + nf * 16 + lrow;
            #pragma unroll
            for (int ss = 0; ss < 2; ++ss)
                bC[nf][ss] = *(const bf16x8*)(WB + n * 128 +
                    ((ss * 64 + lgrp * 16) ^ ((n & 7) << 4)));
        }
        #pragma unroll
        for (int mf = 0; mf < 4; ++mf) {
            int row = mf * 16 + lrow;
            #pragma unroll
            for (int ss = 0; ss < 2; ++ss) {
                int colb = ((2 * s + ss) * 32 + lk) * 4;   // 8 f32 = 32B
                hraw[mf][ss][0] = *(const f32x4*)(HS +
                    ((row * 1280 + colb) ^ ((row & 7) << 4)));
                hraw[mf][ss][1] = *(const f32x4*)(HS +
                    ((row * 1280 + colb + 16) ^ ((row & 7) << 4)));
            }
        }
        WAITLG();                               // reads in regs
        BAR();                                  // all waves done reading WB
        if (s < 4) stage_wp(s + 1);             // refill; lands under MFMA
        bf16x8 hf[4][2];
        #pragma unroll
        for (int mf = 0; mf < 4; ++mf)
            #pragma unroll
            for (int ss = 0; ss < 2; ++ss) {
                unsigned short* hp = (unsigned short*)&hf[mf][ss];
                #pragma unroll
                for (int e = 0; e < 4; ++e) {
                    hp[e]     = f2bf(hraw[mf][ss][0][e]);
                    hp[e + 4] = f2bf(hraw[mf][ss][1][e]);
                }
            }
        __builtin_amdgcn_s_setprio(1);
        #pragma unroll
        for (int ss = 0; ss < 2; ++ss)
            #pragma unroll
            for (int nf = 0; nf < 5; ++nf)
                #pragma unroll
                for (int mf = 0; mf < 4; ++mf)
                    acc[nf][mf] = __builtin_amdgcn_mfma_f32_16x16x32_bf16(
                        bC[nf][ss], hf[mf][ss], acc[nf][mf], 0, 0, 0);
        __builtin_amdgcn_s_setprio(0);
    }
    // s=4's post-read BAR certified HS + WB free; no DMA outstanding.

    // ---- transition: stage U slices 0,1; softmax + P write overlap the DMA
    stage_u(0, U0);
    stage_u(1, U1);

    float inv4[4];
    #pragma unroll
    for (int mf = 0; mf < 4; ++mf) {
        float mx = -1e30f;
        #pragma unroll
        for (int nf = 0; nf < 5; ++nf)
            #pragma unroll
            for (int r = 0; r < 4; ++r) {
                float x = acc[nf][mf][r] - ((const float*)&pv4[nf])[r];
                if (nf == 4 && r >= 1) x = (lgrp == 3) ? -1e30f : x;  // kk 77..79
                acc[nf][mf][r] = x;
                mx = fmaxf(mx, x);
            }
        mx = fmaxf(mx, __shfl_xor(mx, 16));
        mx = fmaxf(mx, __shfl_xor(mx, 32));
        float s = 0.f;
        #pragma unroll
        for (int nf = 0; nf < 5; ++nf)
            #pragma unroll
            for (int r = 0; r < 4; ++r) {
                float e = __expf(acc[nf][mf][r] - mx);
                acc[nf][mf][r] = e; s += e;
            }
        s += __shfl_xor(s, 16);
        s += __shfl_xor(s, 32);
        inv4[mf] = 1.f / s;
    }

    // write P (bf16) into PB: byte = (m*1280 + col*2) ^ ((m&7)<<4)
    #pragma unroll
    for (int mf = 0; mf < 4; ++mf) {
        const int m = mf * 16 + lrow;
        const float inv = inv4[mf];
        #pragma unroll
        for (int nf = 0; nf < 5; ++nf) {
            ushort4 u;
            u.x = f2bf(acc[nf][mf][0] * inv);
            u.y = f2bf(acc[nf][mf][1] * inv);
            u.z = f2bf(acc[nf][mf][2] * inv);
            u.w = f2bf(acc[nf][mf][3] * inv);
            int a = (m * 1280 + (h * KP_ + nf * 16 + lgrp * 4) * 2) ^ ((m & 7) << 4);
            *(ushort4*)(PB + a) = u;
        }
    }
    WAITVL(5);                                  // U slice0 landed + P writes done
    BAR();                                      // P + U0 visible block-wide

    // ---- phase 2: out = P @ U, 10 K=64 slices, 2-buf counted pipeline
    f32x4 acc2[5][2];
    #pragma unroll
    for (int nf = 0; nf < 5; ++nf)
        #pragma unroll
        for (int mf = 0; mf < 2; ++mf) acc2[nf][mf] = (f32x4){0.f, 0.f, 0.f, 0.f};
    #pragma unroll
    for (int t = 0; t < 10; ++t) {
        if (t > 0) {
            if (t < 9) { WAITV(5); } else { WAITV(0); }   // slice t landed
            BAR();
        }
        char* ub = (t & 1) ? U1 : U0;
        bf16x8 pa[2][2], uf[5][2];
        #pragma unroll
        for (int mf = 0; mf < 2; ++mf) {
            int m = mgrp * 32 + mf * 16 + lrow;
            #pragma unroll
            for (int ss = 0; ss < 2; ++ss) {
                int a = (m * 1280 + (t * 128 + ss * 64 + lgrp * 16)) ^ ((m & 7) << 4);
                pa[mf][ss] = *(const bf16x8*)(PB + a);
            }
        }
        #pragma unroll
        for (int nf = 0; nf < 5; ++nf) {
            int c = ngrp * KP_ + nf * 16 + lrow;
            #pragma unroll
            for (int ss = 0; ss < 2; ++ss)
                uf[nf][ss] = *(const bf16x8*)(ub + c * 128 +
                    ((ss * 64 + lgrp * 16) ^ ((c & 7) << 4)));
        }
        WAITLG();                               // reads in regs
        BAR();                                  // all waves done reading ub
        if (t < 8) stage_u(t + 2, ub);          // refill; lands under MFMA
        __builtin_amdgcn_s_setprio(1);
        #pragma unroll
        for (int ss = 0; ss < 2; ++ss)
            #pragma unroll
            for (int nf = 0; nf < 5; ++nf)
                #pragma unroll
                for (int mf = 0; mf < 2; ++mf)
                    acc2[nf][mf] = __builtin_amdgcn_mfma_f32_16x16x32_bf16(
                        pa[mf][ss], uf[nf][ss], acc2[nf][mf], 0, 0, 0);
        __builtin_amdgcn_s_setprio(0);
    }

    // ---- epilogue
    float bov[5];
    #pragma unroll
    for (int nf = 0; nf < 5; ++nf) bov[nf] = bo[ngrp * KP_ + nf * 16 + lrow];
    float* op = out + ((size_t)b * S_ + s0) * C_;
    #pragma unroll
    for (int mf = 0; mf < 2; ++mf)
        #pragma unroll
        for (int r = 0; r < 4; ++r)
            #pragma unroll
            for (int nf = 0; nf < 5; ++nf)
                op[(size_t)(mgrp * 32 + mf * 16 + lgrp * 4 + r) * C_ +
                   ngrp * KP_ + nf * 16 + lrow] = acc2[nf][mf][r] + bov[nf];
}

// ---------------------------------------------------------------- launch
extern "C" void kernel_launch(void* const* d_in, const int* in_sizes, int n_in,
                              void* d_out, int out_size, void* d_ws, size_t ws_size,
                              hipStream_t stream) {
    const float* hs   = (const float*)d_in[0];
    const float* ehs  = (const float*)d_in[1];
    const float* harm = (const float*)d_in[2];
    const float* Wq   = (const float*)d_in[3];
    const float* Wk   = (const float*)d_in[4];
    const float* Wv   = (const float*)d_in[5];
    const float* Wo   = (const float*)d_in[6];
    const float* bo   = (const float*)d_in[7];
    float* out = (float*)d_out;

    char* ws = (char*)d_ws;
    unsigned short* Bmat   = (unsigned short*)(ws + 1966080);   //  7,864,320
    float*          pen    = (float*)        (ws + 9830400);    //      5,120
    unsigned short* Wp     = (unsigned short*)(ws + 9835520);   //  6,553,600
    unsigned short* U      = (unsigned short*)(ws + 16389120);  //  6,553,600

    build_M <<<dim3(3, 8, 16), 256, 0, stream>>>(Wq, Wk, Wv, Wo, Bmat);
    gemm_WpU<<<dim3(320),      512, 0, stream>>>(ehs, harm, Bmat, Wp, U, pen);
    fused_attn<<<dim3(1024),   512, 0, stream>>>(hs, Wp, U, pen, bo, out);
}

// Round 21
// 150.931 us; speedup vs baseline: 1.0728x; 1.0728x over previous
//
#include <hip/hip_runtime.h>
#include <hip/hip_bf16.h>

#define B_ 16
#define S_ 4096
#define C_ 320
#define KK_ 77
#define D_ 768
#define H_ 8
#define DH_ 40
#define KP_ 80           // padded keys per head
#define NP_ (H_ * KP_)   // 640
#define TAU_ 0.1f
#define GAMMA_ 1.0f
#define EPS_ 1e-12f

typedef __bf16 bf16x8 __attribute__((ext_vector_type(8)));
typedef float f32x4 __attribute__((ext_vector_type(4)));
typedef unsigned short ushort8v __attribute__((ext_vector_type(8)));
typedef unsigned int u32;

#define WAITV(N)  asm volatile("s_waitcnt vmcnt(" #N ")" ::: "memory")
#define WAITVL(N) asm volatile("s_waitcnt vmcnt(" #N ") lgkmcnt(0)" ::: "memory")
#define WAITLG()  asm volatile("s_waitcnt lgkmcnt(0)" ::: "memory")
#define BAR()     __builtin_amdgcn_s_barrier()

__device__ __forceinline__ unsigned short f2bf(float f) {
    union { float f; unsigned u; } v; v.f = f;
    unsigned r = v.u + 0x7fffu + ((v.u >> 16) & 1u);
    return (unsigned short)(r >> 16);
}

// async 16B-per-lane global->LDS DMA (lds dest = wave-uniform base + lane*16)
__device__ __forceinline__ void gld16(const unsigned short* g, char* l) {
    __builtin_amdgcn_global_load_lds(
        (const __attribute__((address_space(1))) u32*)g,
        (__attribute__((address_space(3))) u32*)l, 16, 0, 0);
}

// ---------------------------------------------------------------- build_M
// 40-col windows: grid (3, 8, 16)
__global__ __launch_bounds__(256) void build_M(const float* __restrict__ Wq,
        const float* __restrict__ Wk, const float* __restrict__ Wv,
        const float* __restrict__ Wo, unsigned short* __restrict__ Bmat) {
    const int Dk = blockIdx.x * 256 + threadIdx.x;     // 0..767
    const int h = blockIdx.y;
    const int which = blockIdx.z >> 3;
    const int c0 = (blockIdx.z & 7) * 40;
    __shared__ float wlds[40 * 44];
    for (int i = threadIdx.x; i < 40 * DH_; i += 256) {
        int c = i / DH_, d = i % DH_;
        wlds[c * 44 + d] = which
            ? Wo[(size_t)(h * DH_ + d) * C_ + (c0 + c)]
            : Wq[(size_t)(c0 + c) * C_ + h * DH_ + d];
    }
    float a[DH_];
    const float* Arow = (which ? Wv : Wk) + (size_t)Dk * C_ + h * DH_;
    #pragma unroll
    for (int d = 0; d < DH_; ++d) a[d] = Arow[d];
    __syncthreads();
    const float scale = 0.15811388300841898f;          // 1/sqrt(40)
    for (int c = 0; c < 40; ++c) {
        float s = 0.f;
        #pragma unroll
        for (int q = 0; q < 10; ++q) {
            float4 wv4 = *(const float4*)&wlds[c * 44 + q * 4];
            s += a[q * 4 + 0] * wv4.x + a[q * 4 + 1] * wv4.y
               + a[q * 4 + 2] * wv4.z + a[q * 4 + 3] * wv4.w;
        }
        if (!which) s *= scale;
        int n = which * 2560 + h * C_ + c0 + c;
        Bmat[(size_t)n * D_ + Dk] = f2bf(s);
    }
}

// ---------------------------------------------------------------- gemm_WpU
// 320 blocks x 512 threads (16b x 20nt). A staged DIRECTLY from ehs f32
// (inline f32->bf16 convert, kk>=77 zeroed). nt==0 blocks compute penalty.
__global__ __launch_bounds__(512) void gemm_WpU(
        const float* __restrict__ ehs, const float* __restrict__ harm,
        const unsigned short* __restrict__ Bmat,
        unsigned short* __restrict__ Wp, unsigned short* __restrict__ U,
        float* __restrict__ pen) {
    const int id = blockIdx.x;               // 320 = 16 b * 20 nt
    const int b = id & 15, nt = id >> 4;
    const int tid = threadIdx.x, w = tid >> 6, l = tid & 63;
    const int lrow = l & 15, lgrp = l >> 4, lk = lgrp * 8;
    __shared__ unsigned short Al[80 * 768];  // 122880 B, swizzled
    char* lds = (char*)Al;

    const float* Eb = ehs + (size_t)b * KK_ * D_;
    // stage A: 7680 chunks of 8 bf16; chunk ch -> row kk=ch/96, col8=ch%96
    #pragma unroll
    for (int it = 0; it < 15; ++it) {
        int ch = tid + it * 512;             // 0..7679
        int kk = ch / 96, c8 = ch % 96;
        ushort8v v8 = (ushort8v)(unsigned short)0;
        if (kk < KK_) {
            const float4* src = (const float4*)(Eb + (size_t)kk * D_ + c8 * 8);
            float4 a0 = src[0], a1 = src[1];
            v8[0] = f2bf(a0.x); v8[1] = f2bf(a0.y);
            v8[2] = f2bf(a0.z); v8[3] = f2bf(a0.w);
            v8[4] = f2bf(a1.x); v8[5] = f2bf(a1.y);
            v8[6] = f2bf(a1.z); v8[7] = f2bf(a1.w);
        }
        int a = (ch * 16) ^ ((kk & 7) << 4);
        *(ushort8v*)(lds + a) = v8;
    }

    // nt==0: penalty for this batch (wave per row, stride 8)
    if (nt == 0) {
        for (int kk = w; kk < KP_; kk += 8) {
            if (kk < KK_) {
                const float* er = Eb + (size_t)kk * D_;
                float ss = 0.f, dd = 0.f, hh = 0.f;
                #pragma unroll
                for (int j = 0; j < 12; ++j) {
                    float e = er[l + j * 64], hv = harm[l + j * 64];
                    ss += e * e; dd += e * hv; hh += hv * hv;
                }
                #pragma unroll
                for (int off = 32; off; off >>= 1) {
                    ss += __shfl_xor(ss, off);
                    dd += __shfl_xor(dd, off);
                    hh += __shfl_xor(hh, off);
                }
                if (l == 0) {
                    float cs = dd / (fmaxf(sqrtf(ss), EPS_) * fmaxf(sqrtf(hh), EPS_));
                    pen[b * KP_ + kk] = GAMMA_ * fmaxf(cs - TAU_, 0.f);
                }
            } else if (l == 0) {
                pen[b * KP_ + kk] = 0.f;
            }
        }
    }

    const int n0 = nt * 256 + w * 32;
    const unsigned short* Br = Bmat + (size_t)(n0 + lrow) * D_ + lk;
    bf16x8 bC[2], bN[2];
    #pragma unroll
    for (int nf = 0; nf < 2; ++nf)
        bC[nf] = *(const bf16x8*)(Br + (size_t)nf * 16 * D_);
    __syncthreads();

    f32x4 acc[5][2];
    #pragma unroll
    for (int mf = 0; mf < 5; ++mf)
        #pragma unroll
        for (int nf = 0; nf < 2; ++nf) acc[mf][nf] = (f32x4){0.f, 0.f, 0.f, 0.f};
    #pragma unroll
    for (int ks = 0; ks < D_ / 32; ++ks) {
        if (ks < D_ / 32 - 1) {
            #pragma unroll
            for (int nf = 0; nf < 2; ++nf)
                bN[nf] = *(const bf16x8*)(Br + (size_t)nf * 16 * D_ + (ks + 1) * 32);
        }
        bf16x8 af[5];
        #pragma unroll
        for (int mf = 0; mf < 5; ++mf) {
            int row = mf * 16 + lrow;
            int a = (row * 1536 + (ks * 32 + lk) * 2) ^ ((row & 7) << 4);
            af[mf] = *(const bf16x8*)(lds + a);
        }
        __builtin_amdgcn_s_setprio(1);
        #pragma unroll
        for (int mf = 0; mf < 5; ++mf)
            #pragma unroll
            for (int nf = 0; nf < 2; ++nf)
                acc[mf][nf] = __builtin_amdgcn_mfma_f32_16x16x32_bf16(
                    af[mf], bC[nf], acc[mf][nf], 0, 0, 0);
        __builtin_amdgcn_s_setprio(0);
        #pragma unroll
        for (int nf = 0; nf < 2; ++nf) bC[nf] = bN[nf];
    }
    #pragma unroll
    for (int nf = 0; nf < 2; ++nf) {
        const int col = n0 + nf * 16 + lrow;
        if (col < 2560) {
            const int h = col / C_, c = col % C_;
            #pragma unroll
            for (int mf = 0; mf < 5; ++mf)
                #pragma unroll
                for (int r = 0; r < 4; ++r) {
                    int kk = mf * 16 + lgrp * 4 + r;
                    Wp[((size_t)b * NP_ + h * KP_ + kk) * C_ + c] = f2bf(acc[mf][nf][r]);
                }
        } else {
            const int n2 = col - 2560;
            const int h = n2 / C_, c = n2 % C_;
            #pragma unroll
            for (int mf = 0; mf < 5; ++mf)
                #pragma unroll
                for (int r = 0; r < 4; ++r) {
                    int kk = mf * 16 + lgrp * 4 + r;
                    U[((size_t)b * C_ + c) * NP_ + h * KP_ + kk] = f2bf(acc[mf][nf][r]);
                }
        }
    }
}

// ---------------------------------------------------------------- fused attn
// R12/R17/R18 (verified 126us): 1024 blocks x 512 threads (8 waves), 64
// S-rows, 160KB LDS, 1 block/CU. FULL-L2-LINE staging: K=64 slices; source-
// side involution swizzle (q^(n&7)) <-> read XOR ((n&7)<<4).
__global__ __launch_bounds__(512, 2) void fused_attn(
        const float* __restrict__ hs, const unsigned short* __restrict__ Wp,
        const unsigned short* __restrict__ U, const float* __restrict__ pen,
        const float* __restrict__ bo, float* __restrict__ out) {
    const int id = blockIdx.x;                  // 1024 = 8 xcd * 128
    const int xcd = id & 7, rest = id >> 3;
    const int b = xcd * 2 + (rest >> 6);        // 2 batches per XCD
    const int s0 = (rest & 63) * 64;
    __shared__ __align__(16) char smem[163840];
    char* HS = smem;                            // [0,40960)   hs tile (phase 1)
    char* WB = smem + 40960;                    // [40960,122880) Wp K=64 slice
    char* PB = smem;                            // [0,81920)   P (phase 2)
    char* U0 = smem + 81920;                    // [81920,122880)  U slice buf
    char* U1 = smem + 122880;                   // [122880,163840) U slice buf
    const int tid = threadIdx.x, w = tid >> 6, l = tid & 63;
    const int lrow = l & 15, lgrp = l >> 4, lk = lgrp * 8;
    const int h = w;                            // phase-1: wave = head
    const int mgrp = w & 1, ngrp = w >> 1;      // phase-2: 2m x 4n

    const unsigned short* Wpb = Wp + ((size_t)b * NP_) * C_;
    const unsigned short* Ub  = U  + ((size_t)b * C_) * NP_;

    auto stage_wp = [&](int s) {
        #pragma unroll
        for (int j = 0; j < 10; ++j) {
            int ch = w * 640 + j * 64 + l;      // 0..5119
            int n = ch >> 3, q = ch & 7;
            gld16(Wpb + (size_t)n * C_ + s * 64 + ((q ^ (n & 7)) << 3),
                  WB + ch * 16);
        }
    };
    auto stage_u = [&](int t, char* buf) {
        #pragma unroll
        for (int j = 0; j < 5; ++j) {
            int ch = w * 320 + j * 64 + l;      // 0..2559
            int c = ch >> 3, q = ch & 7;
            gld16(Ub + (size_t)c * NP_ + t * 64 + ((q ^ (c & 7)) << 3),
                  buf + ch * 16);
        }
    };

    // ---- prologue: pen + hs loads, convert/ds_write HS, sync, issue slice 0
    float4 pv4[5];
    #pragma unroll
    for (int nf = 0; nf < 5; ++nf)
        pv4[nf] = *(const float4*)(pen + b * KP_ + nf * 16 + lgrp * 4);
    const float4* hv = (const float4*)(hs + ((size_t)b * S_ + s0) * C_);
    #pragma unroll
    for (int it = 0; it < 10; ++it) {           // 10*512 = 5120 float4 = 64x320
        int i = tid + it * 512;
        float4 v = hv[i];
        int r = i / 80, c = (i * 4) % C_;
        ushort4 u;
        u.x = f2bf(v.x); u.y = f2bf(v.y); u.z = f2bf(v.z); u.w = f2bf(v.w);
        int a = (r * 640 + c * 2) ^ ((r & 7) << 4);
        *(ushort4*)(HS + a) = u;
    }
    __syncthreads();        // drains hv/pen vmem + hs ds_writes; HS visible
    stage_wp(0);

    // ---- phase 1: D[kk][m], 5 K=64 slices, single buf; DMA(s+1) || MFMA(s)
    f32x4 acc[5][4];
    #pragma unroll
    for (int nf = 0; nf < 5; ++nf)
        #pragma unroll
        for (int mf = 0; mf < 4; ++mf) acc[nf][mf] = (f32x4){0.f, 0.f, 0.f, 0.f};
    #pragma unroll
    for (int s = 0; s < 5; ++s) {
        WAITV(0);                               // own chunks of slice s done
        BAR();                                  // slice s fully landed
        bf16x8 bC[5][2], hf[4][2];
        #pragma unroll
        for (int nf = 0; nf < 5; ++nf) {
            int n = h * KP_ + nf * 16 + lrow;
            #pragma unroll
            for (int ss = 0; ss < 2; ++ss)
                bC[nf][ss] = *(const bf16x8*)(WB + n * 128 +
                    ((ss * 64 + lgrp * 16) ^ ((n & 7) << 4)));
        }
        #pragma unroll
        for (int mf = 0; mf < 4; ++mf) {
            int row = mf * 16 + lrow;
            #pragma unroll
            for (int ss = 0; ss < 2; ++ss) {
                int ks32 = 2 * s + ss;
                int a = (row * 640 + (ks32 * 32 + lk) * 2) ^ ((row & 7) << 4);
                hf[mf][ss] = *(const bf16x8*)(HS + a);
            }
        }
        WAITLG();                               // reads in regs
        BAR();                                  // all waves done reading WB
        if (s < 4) stage_wp(s + 1);             // refill; lands under MFMA
        __builtin_amdgcn_s_setprio(1);
        #pragma unroll
        for (int ss = 0; ss < 2; ++ss)
            #pragma unroll
            for (int nf = 0; nf < 5; ++nf)
                #pragma unroll
                for (int mf = 0; mf < 4; ++mf)
                    acc[nf][mf] = __builtin_amdgcn_mfma_f32_16x16x32_bf16(
                        bC[nf][ss], hf[mf][ss], acc[nf][mf], 0, 0, 0);
        __builtin_amdgcn_s_setprio(0);
    }
    // s=4's post-read BAR certified HS + WB free; no DMA outstanding.

    // ---- transition: stage U slices 0,1; softmax + P write overlap the DMA
    stage_u(0, U0);
    stage_u(1, U1);

    float inv4[4];
    #pragma unroll
    for (int mf = 0; mf < 4; ++mf) {
        float mx = -1e30f;
        #pragma unroll
        for (int nf = 0; nf < 5; ++nf)
            #pragma unroll
            for (int r = 0; r < 4; ++r) {
                float x = acc[nf][mf][r] - ((const float*)&pv4[nf])[r];
                if (nf == 4 && r >= 1) x = (lgrp == 3) ? -1e30f : x;  // kk 77..79
                acc[nf][mf][r] = x;
                mx = fmaxf(mx, x);
            }
        mx = fmaxf(mx, __shfl_xor(mx, 16));
        mx = fmaxf(mx, __shfl_xor(mx, 32));
        float s = 0.f;
        #pragma unroll
        for (int nf = 0; nf < 5; ++nf)
            #pragma unroll
            for (int r = 0; r < 4; ++r) {
                float e = __expf(acc[nf][mf][r] - mx);
                acc[nf][mf][r] = e; s += e;
            }
        s += __shfl_xor(s, 16);
        s += __shfl_xor(s, 32);
        inv4[mf] = 1.f / s;
    }

    // write P (bf16) into PB: byte = (m*1280 + col*2) ^ ((m&7)<<4)
    #pragma unroll
    for (int mf = 0; mf < 4; ++mf) {
        const int m = mf * 16 + lrow;
        const float inv = inv4[mf];
        #pragma unroll
        for (int nf = 0; nf < 5; ++nf) {
            ushort4 u;
            u.x = f2bf(acc[nf][mf][0] * inv);
            u.y = f2bf(acc[nf][mf][1] * inv);
            u.z = f2bf(acc[nf][mf][2] * inv);
            u.w = f2bf(acc[nf][mf][3] * inv);
            int a = (m * 1280 + (h * KP_ + nf * 16 + lgrp * 4) * 2) ^ ((m & 7) << 4);
            *(ushort4*)(PB + a) = u;
        }
    }
    WAITVL(5);                                  // U slice0 landed + P writes done
    BAR();                                      // P + U0 visible block-wide

    // ---- phase 2: out = P @ U, 10 K=64 slices, 2-buf counted pipeline
    f32x4 acc2[5][2];
    #pragma unroll
    for (int nf = 0; nf < 5; ++nf)
        #pragma unroll
        for (int mf = 0; mf < 2; ++mf) acc2[nf][mf] = (f32x4){0.f, 0.f, 0.f, 0.f};
    #pragma unroll
    for (int t = 0; t < 10; ++t) {
        if (t > 0) {
            if (t < 9) { WAITV(5); } else { WAITV(0); }   // slice t landed
            BAR();
        }
        char* ub = (t & 1) ? U1 : U0;
        bf16x8 pa[2][2], uf[5][2];
        #pragma unroll
        for (int mf = 0; mf < 2; ++mf) {
            int m = mgrp * 32 + mf * 16 + lrow;
            #pragma unroll
            for (int ss = 0; ss < 2; ++ss) {
                int a = (m * 1280 + (t * 128 + ss * 64 + lgrp * 16)) ^ ((m & 7) << 4);
                pa[mf][ss] = *(const bf16x8*)(PB + a);
            }
        }
        #pragma unroll
        for (int nf = 0; nf < 5; ++nf) {
            int c = ngrp * KP_ + nf * 16 + lrow;
            #pragma unroll
            for (int ss = 0; ss < 2; ++ss)
                uf[nf][ss] = *(const bf16x8*)(ub + c * 128 +
                    ((ss * 64 + lgrp * 16) ^ ((c & 7) << 4)));
        }
        WAITLG();                               // reads in regs
        BAR();                                  // all waves done reading ub
        if (t < 8) stage_u(t + 2, ub);          // refill; lands under MFMA
        __builtin_amdgcn_s_setprio(1);
        #pragma unroll
        for (int ss = 0; ss < 2; ++ss)
            #pragma unroll
            for (int nf = 0; nf < 5; ++nf)
                #pragma unroll
                for (int mf = 0; mf < 2; ++mf)
                    acc2[nf][mf] = __builtin_amdgcn_mfma_f32_16x16x32_bf16(
                        pa[mf][ss], uf[nf][ss], acc2[nf][mf], 0, 0, 0);
        __builtin_amdgcn_s_setprio(0);
    }

    // ---- epilogue
    float bov[5];
    #pragma unroll
    for (int nf = 0; nf < 5; ++nf) bov[nf] = bo[ngrp * KP_ + nf * 16 + lrow];
    float* op = out + ((size_t)b * S_ + s0) * C_;
    #pragma unroll
    for (int mf = 0; mf < 2; ++mf)
        #pragma unroll
        for (int r = 0; r < 4; ++r)
            #pragma unroll
            for (int nf = 0; nf < 5; ++nf)
                op[(size_t)(mgrp * 32 + mf * 16 + lgrp * 4 + r) * C_ +
                   ngrp * KP_ + nf * 16 + lrow] = acc2[nf][mf][r] + bov[nf];
}

// ---------------------------------------------------------------- launch
extern "C" void kernel_launch(void* const* d_in, const int* in_sizes, int n_in,
                              void* d_out, int out_size, void* d_ws, size_t ws_size,
                              hipStream_t stream) {
    const float* hs   = (const float*)d_in[0];
    const float* ehs  = (const float*)d_in[1];
    const float* harm = (const float*)d_in[2];
    const float* Wq   = (const float*)d_in[3];
    const float* Wk   = (const float*)d_in[4];
    const float* Wv   = (const float*)d_in[5];
    const float* Wo   = (const float*)d_in[6];
    const float* bo   = (const float*)d_in[7];
    float* out = (float*)d_out;

    char* ws = (char*)d_ws;
    unsigned short* Bmat   = (unsigned short*)(ws + 1966080);   //  7,864,320
    float*          pen    = (float*)        (ws + 9830400);    //      5,120
    unsigned short* Wp     = (unsigned short*)(ws + 9835520);   //  6,553,600
    unsigned short* U      = (unsigned short*)(ws + 16389120);  //  6,553,600

    build_M <<<dim3(3, 8, 16), 256, 0, stream>>>(Wq, Wk, Wv, Wo, Bmat);
    gemm_WpU<<<dim3(320),      512, 0, stream>>>(ehs, harm, Bmat, Wp, U, pen);
    fused_attn<<<dim3(1024),   512, 0, stream>>>(hs, Wp, U, pen, bo, out);
}